// Round 3
// baseline (167.630 us; speedup 1.0000x reference)
//
#include <hip/hip_runtime.h>
#include <stdint.h>

typedef __bf16 bf16_t;
typedef bf16_t bf16x8 __attribute__((ext_vector_type(8)));
typedef float floatx4 __attribute__((ext_vector_type(4)));

__device__ __forceinline__ uint16_t f2bf(float f){
  union { float f; uint32_t i; } c; c.f = f;
  uint32_t r = (c.i + 0x7FFFu + ((c.i >> 16) & 1u)) >> 16;
  return (uint16_t)r;
}
__device__ __forceinline__ float bflo(uint32_t u){
  union { uint32_t i; float f; } c; c.i = u << 16; return c.f;
}
__device__ __forceinline__ float bfhi(uint32_t u){
  union { uint32_t i; float f; } c; c.i = u & 0xffff0000u; return c.f;
}

// ---------- elementwise fp32 -> bf16 convert, 8 elems/thread ----------
__global__ __launch_bounds__(256) void convert_f32_bf16(
    const float* __restrict__ src, uint16_t* __restrict__ dst)
{
  int idx = blockIdx.x * 256 + threadIdx.x;   // one uint4 (8 bf16) per thread
  const float4* s = (const float4*)src + (size_t)idx * 2;
  float4 a = s[0], b = s[1];
  uint4 pk;
  pk.x = (uint32_t)f2bf(a.x) | ((uint32_t)f2bf(a.y) << 16);
  pk.y = (uint32_t)f2bf(a.z) | ((uint32_t)f2bf(a.w) << 16);
  pk.z = (uint32_t)f2bf(b.x) | ((uint32_t)f2bf(b.y) << 16);
  pk.w = (uint32_t)f2bf(b.z) | ((uint32_t)f2bf(b.w) << 16);
  ((uint4*)dst)[idx] = pk;
}

// ---------- transpose + convert: dst[n*K+k] (bf16) = src[k*N+n] (fp32) ----------
__global__ __launch_bounds__(256) void transpose_f32_bf16(
    const float* __restrict__ src, uint16_t* __restrict__ dst, int K, int N)
{
  __shared__ uint16_t tile[64][65];
  int k0 = blockIdx.x * 64, n0 = blockIdx.y * 64;
  for (int idx = threadIdx.x; idx < 64 * 64; idx += 256){
    int r = idx >> 6, c = idx & 63;
    tile[r][c] = f2bf(src[(k0 + r) * N + n0 + c]);
  }
  __syncthreads();
  for (int idx = threadIdx.x; idx < 64 * 64; idx += 256){
    int r = idx >> 6, c = idx & 63;
    dst[(n0 + r) * K + k0 + c] = tile[c][r];
  }
}

// ---------- GEMM: C[M,N] = A[M,256] (bf16) * Bt[N,256]^T (bf16) + bias (fp32) ----------
#define KDIM 256
#define KHALF 128
#define KP 136  // LDS row stride (bf16 elems): 16B-aligned rows, 2-way-free bank aliasing

template<int OUTF32>
__global__ __launch_bounds__(256) void gemm_bt_bias(
    const uint16_t* __restrict__ A,
    const uint16_t* __restrict__ Bt,
    const float* __restrict__ bias,
    void* __restrict__ Cv,
    int N)
{
  __shared__ uint16_t Al[64 * KP];
  __shared__ uint16_t Bl[64 * KP];
  const int m0 = blockIdx.x * 64, n0 = blockIdx.y * 64;
  const int t = threadIdx.x;
  const int lane = t & 63;
  const int wave = t >> 6;
  const int wm = (wave & 1) * 32, wn = (wave >> 1) * 32;
  const int fr = lane & 15;        // fragment row (m or n)
  const int q8 = (lane >> 4) * 8;  // k sub-offset

  floatx4 acc00 = {0.f,0.f,0.f,0.f}, acc01 = {0.f,0.f,0.f,0.f};
  floatx4 acc10 = {0.f,0.f,0.f,0.f}, acc11 = {0.f,0.f,0.f,0.f};

  const int sr = t >> 2;          // staging row 0..63
  const int sc = (t & 3) * 32;    // staging col base within 128

  for (int ko = 0; ko < 2; ko++){
    if (ko) __syncthreads();
    const uint16_t* ga = A  + (m0 + sr) * KDIM + ko * KHALF + sc;
    const uint16_t* gb = Bt + (n0 + sr) * KDIM + ko * KHALF + sc;
    uint16_t* la = Al + sr * KP + sc;
    uint16_t* lb = Bl + sr * KP + sc;
    #pragma unroll
    for (int ii = 0; ii < 32; ii += 8){
      *(bf16x8*)(la + ii) = *(const bf16x8*)(ga + ii);
      *(bf16x8*)(lb + ii) = *(const bf16x8*)(gb + ii);
    }
    __syncthreads();
    #pragma unroll
    for (int kk = 0; kk < KHALF; kk += 32){
      bf16x8 a0 = *(const bf16x8*)(Al + (wm + fr)      * KP + kk + q8);
      bf16x8 a1 = *(const bf16x8*)(Al + (wm + 16 + fr) * KP + kk + q8);
      bf16x8 b0 = *(const bf16x8*)(Bl + (wn + fr)      * KP + kk + q8);
      bf16x8 b1 = *(const bf16x8*)(Bl + (wn + 16 + fr) * KP + kk + q8);
      acc00 = __builtin_amdgcn_mfma_f32_16x16x32_bf16(a0, b0, acc00, 0, 0, 0);
      acc01 = __builtin_amdgcn_mfma_f32_16x16x32_bf16(a0, b1, acc01, 0, 0, 0);
      acc10 = __builtin_amdgcn_mfma_f32_16x16x32_bf16(a1, b0, acc10, 0, 0, 0);
      acc11 = __builtin_amdgcn_mfma_f32_16x16x32_bf16(a1, b1, acc11, 0, 0, 0);
    }
  }

  // epilogue: C/D layout col=lane&15, row=(lane>>4)*4+r  [verified m89/m91]
  const int ccol = lane & 15;
  const int crow = (lane >> 4) * 4;
  float bv0 = bias[n0 + wn + ccol];
  float bv1 = bias[n0 + wn + 16 + ccol];
  #pragma unroll
  for (int r2 = 0; r2 < 4; r2++){
    int rA = m0 + wm + crow + r2;
    int rB = rA + 16;
    if (OUTF32){
      float* C = (float*)Cv;
      C[rA * N + n0 + wn + ccol]      = acc00[r2] + bv0;
      C[rA * N + n0 + wn + 16 + ccol] = acc01[r2] + bv1;
      C[rB * N + n0 + wn + ccol]      = acc10[r2] + bv0;
      C[rB * N + n0 + wn + 16 + ccol] = acc11[r2] + bv1;
    } else {
      uint16_t* C = (uint16_t*)Cv;
      C[rA * N + n0 + wn + ccol]      = f2bf(acc00[r2] + bv0);
      C[rA * N + n0 + wn + 16 + ccol] = f2bf(acc01[r2] + bv1);
      C[rB * N + n0 + wn + ccol]      = f2bf(acc10[r2] + bv0);
      C[rB * N + n0 + wn + 16 + ccol] = f2bf(acc11[r2] + bv1);
    }
  }
}

// ---------- NATTEN attention: one thread per (b, head, i, j) query ----------
// 49 logits in registers (7x7 loops fully unrolled), fp32 math, bf16 qkv in / attn out
__global__ __launch_bounds__(64) void natten_kernel(
    const uint16_t* __restrict__ qkv,   // [6272][768] bf16: q|k|v each [8 heads][32]
    const float* __restrict__ rpb0,     // [4][13][13] fp32
    const float* __restrict__ rpb1,     // [4][13][13] fp32
    uint16_t* __restrict__ attn_out)    // [6272][256] bf16
{
  const int t = threadIdx.x;
  const int j = blockIdx.x * 8 + (t & 7);
  const int i = blockIdx.y * 8 + (t >> 3);
  const int z = blockIdx.z;           // b*8 + h
  const int b = z >> 3, h = z & 7;
  const int split = h >> 2;
  const int dil = split + 1;          // DIL = (1, 2)
  const float* rpb = (split ? rpb1 : rpb0) + (h & 3) * 169;

  const int ri = i % dil, pi = i / dil;
  const int rj = j % dil, pj = j / dil;
  const int Lri = (56 - ri + dil - 1) / dil;
  const int Lrj = (56 - rj + dil - 1) / dil;
  const int psi = min(max(pi - 3, 0), Lri - 7);
  const int psj = min(max(pj - 3, 0), Lrj - 7);
  const int bi0 = psi - pi + 6, bj0 = psj - pj + 6;
  const int ni0 = psi * dil + ri, nj0 = psj * dil + rj;

  const int tok = (b * 56 + i) * 56 + j;
  const float scale = 0.17677669529663687f;  // 32^-0.5

  float qv[32];
  {
    const uint4* qp = (const uint4*)(qkv + (size_t)tok * 768 + h * 32);
    #pragma unroll
    for (int c = 0; c < 4; c++){
      uint4 u = qp[c];
      qv[c*8+0] = bflo(u.x) * scale; qv[c*8+1] = bfhi(u.x) * scale;
      qv[c*8+2] = bflo(u.y) * scale; qv[c*8+3] = bfhi(u.y) * scale;
      qv[c*8+4] = bflo(u.z) * scale; qv[c*8+5] = bfhi(u.z) * scale;
      qv[c*8+6] = bflo(u.w) * scale; qv[c*8+7] = bfhi(u.w) * scale;
    }
  }

  float lg[49];
  float mx = -1e30f;
  #pragma unroll
  for (int ai = 0; ai < 7; ai++){
    int rowb = (b * 56 + ni0 + ai * dil) * 56;
    int rpi = (bi0 + ai) * 13 + bj0;
    #pragma unroll
    for (int aj = 0; aj < 7; aj++){
      int tk = rowb + nj0 + aj * dil;
      const uint4* kp = (const uint4*)(qkv + (size_t)tk * 768 + 256 + h * 32);
      float dot = 0.f;
      #pragma unroll
      for (int c = 0; c < 4; c++){
        uint4 u = kp[c];
        dot += qv[c*8+0] * bflo(u.x); dot += qv[c*8+1] * bfhi(u.x);
        dot += qv[c*8+2] * bflo(u.y); dot += qv[c*8+3] * bfhi(u.y);
        dot += qv[c*8+4] * bflo(u.z); dot += qv[c*8+5] * bfhi(u.z);
        dot += qv[c*8+6] * bflo(u.w); dot += qv[c*8+7] * bfhi(u.w);
      }
      float l = dot + rpb[rpi + aj];
      lg[ai * 7 + aj] = l;
      mx = fmaxf(mx, l);
    }
  }

  float ssum = 0.f;
  #pragma unroll
  for (int a = 0; a < 49; a++){
    float e = __expf(lg[a] - mx);
    lg[a] = e;
    ssum += e;
  }
  float inv = 1.0f / ssum;

  float ov[32];
  #pragma unroll
  for (int d = 0; d < 32; d++) ov[d] = 0.f;

  #pragma unroll
  for (int ai = 0; ai < 7; ai++){
    int rowb = (b * 56 + ni0 + ai * dil) * 56;
    #pragma unroll
    for (int aj = 0; aj < 7; aj++){
      int tk = rowb + nj0 + aj * dil;
      const uint4* vp = (const uint4*)(qkv + (size_t)tk * 768 + 512 + h * 32);
      float w = lg[ai * 7 + aj] * inv;
      #pragma unroll
      for (int c = 0; c < 4; c++){
        uint4 u = vp[c];
        ov[c*8+0] += w * bflo(u.x); ov[c*8+1] += w * bfhi(u.x);
        ov[c*8+2] += w * bflo(u.y); ov[c*8+3] += w * bfhi(u.y);
        ov[c*8+4] += w * bflo(u.z); ov[c*8+5] += w * bfhi(u.z);
        ov[c*8+6] += w * bflo(u.w); ov[c*8+7] += w * bfhi(u.w);
      }
    }
  }

  uint16_t* op = attn_out + (size_t)tok * 256 + h * 32;
  #pragma unroll
  for (int c = 0; c < 4; c++){
    uint4 pk;
    pk.x = (uint32_t)f2bf(ov[c*8+0]) | ((uint32_t)f2bf(ov[c*8+1]) << 16);
    pk.y = (uint32_t)f2bf(ov[c*8+2]) | ((uint32_t)f2bf(ov[c*8+3]) << 16);
    pk.z = (uint32_t)f2bf(ov[c*8+4]) | ((uint32_t)f2bf(ov[c*8+5]) << 16);
    pk.w = (uint32_t)f2bf(ov[c*8+6]) | ((uint32_t)f2bf(ov[c*8+7]) << 16);
    *(uint4*)(op + c * 8) = pk;
  }
}

extern "C" void kernel_launch(void* const* d_in, const int* in_sizes, int n_in,
                              void* d_out, int out_size, void* d_ws, size_t ws_size,
                              hipStream_t stream)
{
  (void)in_sizes; (void)n_in; (void)out_size; (void)ws_size;
  const float* x      = (const float*)d_in[0];   // [2,56,56,256]
  const float* w_qkv  = (const float*)d_in[1];   // [256,768]
  const float* b_qkv  = (const float*)d_in[2];   // [768]
  const float* w_proj = (const float*)d_in[3];   // [256,256]
  const float* b_proj = (const float*)d_in[4];   // [256]
  const float* rpb0   = (const float*)d_in[5];   // [4,13,13]
  const float* rpb1   = (const float*)d_in[6];   // [4,13,13]
  float* out = (float*)d_out;                    // [2,56,56,256] fp32

  // ws layout (bf16 elems): wqkvT | wprojT | xb | qkv | attn  => ~15.8 MB
  uint16_t* wqkvT  = (uint16_t*)d_ws;                    // 768*256
  uint16_t* wprojT = wqkvT + 768 * 256;                  // 256*256
  uint16_t* xb     = wprojT + 256 * 256;                 // 6272*256
  uint16_t* qkv    = xb + (size_t)6272 * 256;            // 6272*768
  uint16_t* attn   = qkv + (size_t)6272 * 768;           // 6272*256

  convert_f32_bf16<<<dim3(784), 256, 0, stream>>>(x, xb);          // 6272*256/8/256
  transpose_f32_bf16<<<dim3(4, 12), 256, 0, stream>>>(w_qkv, wqkvT, 256, 768);
  transpose_f32_bf16<<<dim3(4, 4),  256, 0, stream>>>(w_proj, wprojT, 256, 256);
  gemm_bt_bias<0><<<dim3(98, 12), 256, 0, stream>>>(xb, wqkvT, b_qkv, qkv, 768);
  natten_kernel<<<dim3(7, 7, 16), 64, 0, stream>>>(qkv, rpb0, rpb1, attn);
  gemm_bt_bias<1><<<dim3(98, 4), 256, 0, stream>>>(attn, wprojT, b_proj, out, 256);
}

// Round 4
// 139.246 us; speedup vs baseline: 1.2038x; 1.2038x over previous
//
#include <hip/hip_runtime.h>
#include <stdint.h>

typedef __bf16 bf16_t;
typedef bf16_t bf16x8 __attribute__((ext_vector_type(8)));
typedef float floatx4 __attribute__((ext_vector_type(4)));

__device__ __forceinline__ uint16_t f2bf(float f){
  union { float f; uint32_t i; } c; c.f = f;
  uint32_t r = (c.i + 0x7FFFu + ((c.i >> 16) & 1u)) >> 16;
  return (uint16_t)r;
}
__device__ __forceinline__ float bflo(uint32_t u){
  union { uint32_t i; float f; } c; c.i = u << 16; return c.f;
}
__device__ __forceinline__ float bfhi(uint32_t u){
  union { uint32_t i; float f; } c; c.i = u & 0xffff0000u; return c.f;
}

// ---------- elementwise fp32 -> bf16 convert, 8 elems/thread ----------
__global__ __launch_bounds__(256) void convert_f32_bf16(
    const float* __restrict__ src, uint16_t* __restrict__ dst)
{
  int idx = blockIdx.x * 256 + threadIdx.x;   // one uint4 (8 bf16) per thread
  const float4* s = (const float4*)src + (size_t)idx * 2;
  float4 a = s[0], b = s[1];
  uint4 pk;
  pk.x = (uint32_t)f2bf(a.x) | ((uint32_t)f2bf(a.y) << 16);
  pk.y = (uint32_t)f2bf(a.z) | ((uint32_t)f2bf(a.w) << 16);
  pk.z = (uint32_t)f2bf(b.x) | ((uint32_t)f2bf(b.y) << 16);
  pk.w = (uint32_t)f2bf(b.z) | ((uint32_t)f2bf(b.w) << 16);
  ((uint4*)dst)[idx] = pk;
}

// ---------- transpose + convert: dst[n*K+k] (bf16) = src[k*N+n] (fp32) ----------
__global__ __launch_bounds__(256) void transpose_f32_bf16(
    const float* __restrict__ src, uint16_t* __restrict__ dst, int K, int N)
{
  __shared__ uint16_t tile[64][65];
  int k0 = blockIdx.x * 64, n0 = blockIdx.y * 64;
  for (int idx = threadIdx.x; idx < 64 * 64; idx += 256){
    int r = idx >> 6, c = idx & 63;
    tile[r][c] = f2bf(src[(k0 + r) * N + n0 + c]);
  }
  __syncthreads();
  for (int idx = threadIdx.x; idx < 64 * 64; idx += 256){
    int r = idx >> 6, c = idx & 63;
    dst[(n0 + r) * K + k0 + c] = tile[c][r];
  }
}

// ---------- GEMM: C[M,N] = A[M,256] (bf16) * Bt[N,256]^T (bf16) + bias (fp32) ----------
#define KDIM 256
#define KHALF 128
#define KP 136  // LDS row stride (bf16 elems): 16B-aligned rows, 2-way-free bank aliasing

template<int OUTF32>
__global__ __launch_bounds__(256) void gemm_bt_bias(
    const uint16_t* __restrict__ A,
    const uint16_t* __restrict__ Bt,
    const float* __restrict__ bias,
    void* __restrict__ Cv,
    int N)
{
  __shared__ uint16_t Al[64 * KP];
  __shared__ uint16_t Bl[64 * KP];
  const int m0 = blockIdx.x * 64, n0 = blockIdx.y * 64;
  const int t = threadIdx.x;
  const int lane = t & 63;
  const int wave = t >> 6;
  const int wm = (wave & 1) * 32, wn = (wave >> 1) * 32;
  const int fr = lane & 15;        // fragment row (m or n)
  const int q8 = (lane >> 4) * 8;  // k sub-offset

  floatx4 acc00 = {0.f,0.f,0.f,0.f}, acc01 = {0.f,0.f,0.f,0.f};
  floatx4 acc10 = {0.f,0.f,0.f,0.f}, acc11 = {0.f,0.f,0.f,0.f};

  const int sr = t >> 2;          // staging row 0..63
  const int sc = (t & 3) * 32;    // staging col base within 128

  for (int ko = 0; ko < 2; ko++){
    if (ko) __syncthreads();
    const uint16_t* ga = A  + (m0 + sr) * KDIM + ko * KHALF + sc;
    const uint16_t* gb = Bt + (n0 + sr) * KDIM + ko * KHALF + sc;
    uint16_t* la = Al + sr * KP + sc;
    uint16_t* lb = Bl + sr * KP + sc;
    #pragma unroll
    for (int ii = 0; ii < 32; ii += 8){
      *(bf16x8*)(la + ii) = *(const bf16x8*)(ga + ii);
      *(bf16x8*)(lb + ii) = *(const bf16x8*)(gb + ii);
    }
    __syncthreads();
    #pragma unroll
    for (int kk = 0; kk < KHALF; kk += 32){
      bf16x8 a0 = *(const bf16x8*)(Al + (wm + fr)      * KP + kk + q8);
      bf16x8 a1 = *(const bf16x8*)(Al + (wm + 16 + fr) * KP + kk + q8);
      bf16x8 b0 = *(const bf16x8*)(Bl + (wn + fr)      * KP + kk + q8);
      bf16x8 b1 = *(const bf16x8*)(Bl + (wn + 16 + fr) * KP + kk + q8);
      acc00 = __builtin_amdgcn_mfma_f32_16x16x32_bf16(a0, b0, acc00, 0, 0, 0);
      acc01 = __builtin_amdgcn_mfma_f32_16x16x32_bf16(a0, b1, acc01, 0, 0, 0);
      acc10 = __builtin_amdgcn_mfma_f32_16x16x32_bf16(a1, b0, acc10, 0, 0, 0);
      acc11 = __builtin_amdgcn_mfma_f32_16x16x32_bf16(a1, b1, acc11, 0, 0, 0);
    }
  }

  // epilogue: C/D layout col=lane&15, row=(lane>>4)*4+r  [verified m89/m91]
  const int ccol = lane & 15;
  const int crow = (lane >> 4) * 4;
  float bv0 = bias[n0 + wn + ccol];
  float bv1 = bias[n0 + wn + 16 + ccol];
  #pragma unroll
  for (int r2 = 0; r2 < 4; r2++){
    int rA = m0 + wm + crow + r2;
    int rB = rA + 16;
    if (OUTF32){
      float* C = (float*)Cv;
      C[rA * N + n0 + wn + ccol]      = acc00[r2] + bv0;
      C[rA * N + n0 + wn + 16 + ccol] = acc01[r2] + bv1;
      C[rB * N + n0 + wn + ccol]      = acc10[r2] + bv0;
      C[rB * N + n0 + wn + 16 + ccol] = acc11[r2] + bv1;
    } else {
      uint16_t* C = (uint16_t*)Cv;
      C[rA * N + n0 + wn + ccol]      = f2bf(acc00[r2] + bv0);
      C[rA * N + n0 + wn + 16 + ccol] = f2bf(acc01[r2] + bv1);
      C[rB * N + n0 + wn + ccol]      = f2bf(acc10[r2] + bv0);
      C[rB * N + n0 + wn + 16 + ccol] = f2bf(acc11[r2] + bv1);
    }
  }
}

// ---------- NATTEN attention v2: 4 lanes per query ----------
// Block = 256 threads = 4 waves; each wave = 16 queries x 4 lanes.
// Lane owns 8 of 32 head-dims; QK partial dots reduced via shfl_xor(1,2);
// 49 logits distributed 13/lane (owner = key%4); AV weights via shfl broadcast.
__global__ __launch_bounds__(256, 4) void natten_kernel(
    const uint16_t* __restrict__ qkv,   // [6272][768] bf16: q|k|v each [8 heads][32]
    const float* __restrict__ rpb0,     // [4][13][13] fp32
    const float* __restrict__ rpb1,     // [4][13][13] fp32
    uint16_t* __restrict__ attn_out)    // [6272][256] bf16
{
  const int t = threadIdx.x;
  const int c  = t & 3;                 // dim-group 0..3 (8 dims each)
  const int qi = t >> 2;                // query within 8x8 tile, 0..63
  const int j = blockIdx.x * 8 + (qi & 7);
  const int i = blockIdx.y * 8 + (qi >> 3);
  const int z = blockIdx.z;             // b*8 + h
  const int b = z >> 3, h = z & 7;
  const int split = h >> 2;
  const int dil = split + 1;            // DIL = (1, 2)
  const float* rpb = (split ? rpb1 : rpb0) + (h & 3) * 169;

  const int ri = i % dil, pi = i / dil;
  const int rj = j % dil, pj = j / dil;
  const int Lri = (56 - ri + dil - 1) / dil;
  const int Lrj = (56 - rj + dil - 1) / dil;
  const int psi = min(max(pi - 3, 0), Lri - 7);
  const int psj = min(max(pj - 3, 0), Lrj - 7);
  const int bi0 = psi - pi + 6, bj0 = psj - pj + 6;
  const int ni0 = psi * dil + ri, nj0 = psj * dil + rj;

  const int tok = (b * 56 + i) * 56 + j;
  const float scale = 0.17677669529663687f;  // 32^-0.5

  float qv[8];
  {
    uint4 u = *(const uint4*)(qkv + (size_t)tok * 768 + h * 32 + c * 8);
    qv[0] = bflo(u.x) * scale; qv[1] = bfhi(u.x) * scale;
    qv[2] = bflo(u.y) * scale; qv[3] = bfhi(u.y) * scale;
    qv[4] = bflo(u.z) * scale; qv[5] = bfhi(u.z) * scale;
    qv[6] = bflo(u.w) * scale; qv[7] = bfhi(u.w) * scale;
  }

  float lgl[13];
  lgl[12] = -1e30f;   // only lane c==0 owns key 48; others keep -inf
  #pragma unroll
  for (int ai = 0; ai < 7; ai++){
    int rowb = (b * 56 + ni0 + ai * dil) * 56;
    int rpi = (bi0 + ai) * 13 + bj0;
    #pragma unroll
    for (int aj = 0; aj < 7; aj++){
      const int a = ai * 7 + aj;
      int tk = rowb + nj0 + aj * dil;
      uint4 u = *(const uint4*)(qkv + (size_t)tk * 768 + 256 + h * 32 + c * 8);
      float d = qv[0] * bflo(u.x) + qv[1] * bfhi(u.x)
              + qv[2] * bflo(u.y) + qv[3] * bfhi(u.y)
              + qv[4] * bflo(u.z) + qv[5] * bfhi(u.z)
              + qv[6] * bflo(u.w) + qv[7] * bfhi(u.w);
      d += __shfl_xor(d, 1);
      d += __shfl_xor(d, 2);
      d += rpb[rpi + aj];
      if ((a & 3) == c) lgl[a >> 2] = d;   // predicated static-index store
    }
  }

  // distributed softmax over the 4-lane group
  float mx = lgl[0];
  #pragma unroll
  for (int s = 1; s < 13; s++) mx = fmaxf(mx, lgl[s]);
  mx = fmaxf(mx, __shfl_xor(mx, 1));
  mx = fmaxf(mx, __shfl_xor(mx, 2));
  float ssum = 0.f;
  #pragma unroll
  for (int s = 0; s < 13; s++){
    float e = __expf(lgl[s] - mx);   // -1e30 slot -> exp underflows to 0
    lgl[s] = e;
    ssum += e;
  }
  ssum += __shfl_xor(ssum, 1);
  ssum += __shfl_xor(ssum, 2);
  float inv = 1.0f / ssum;

  float ov[8];
  #pragma unroll
  for (int d = 0; d < 8; d++) ov[d] = 0.f;

  const int lane4 = t & 60;   // (lane & ~3) within wave
  #pragma unroll
  for (int ai = 0; ai < 7; ai++){
    int rowb = (b * 56 + ni0 + ai * dil) * 56;
    #pragma unroll
    for (int aj = 0; aj < 7; aj++){
      const int a = ai * 7 + aj;
      int tk = rowb + nj0 + aj * dil;
      uint4 u = *(const uint4*)(qkv + (size_t)tk * 768 + 512 + h * 32 + c * 8);
      float w = __shfl(lgl[a >> 2], lane4 | (a & 3)) * inv;
      ov[0] += w * bflo(u.x); ov[1] += w * bfhi(u.x);
      ov[2] += w * bflo(u.y); ov[3] += w * bfhi(u.y);
      ov[4] += w * bflo(u.z); ov[5] += w * bfhi(u.z);
      ov[6] += w * bflo(u.w); ov[7] += w * bfhi(u.w);
    }
  }

  uint4 pk;
  pk.x = (uint32_t)f2bf(ov[0]) | ((uint32_t)f2bf(ov[1]) << 16);
  pk.y = (uint32_t)f2bf(ov[2]) | ((uint32_t)f2bf(ov[3]) << 16);
  pk.z = (uint32_t)f2bf(ov[4]) | ((uint32_t)f2bf(ov[5]) << 16);
  pk.w = (uint32_t)f2bf(ov[6]) | ((uint32_t)f2bf(ov[7]) << 16);
  *(uint4*)(attn_out + (size_t)tok * 256 + h * 32 + c * 8) = pk;
}

extern "C" void kernel_launch(void* const* d_in, const int* in_sizes, int n_in,
                              void* d_out, int out_size, void* d_ws, size_t ws_size,
                              hipStream_t stream)
{
  (void)in_sizes; (void)n_in; (void)out_size; (void)ws_size;
  const float* x      = (const float*)d_in[0];   // [2,56,56,256]
  const float* w_qkv  = (const float*)d_in[1];   // [256,768]
  const float* b_qkv  = (const float*)d_in[2];   // [768]
  const float* w_proj = (const float*)d_in[3];   // [256,256]
  const float* b_proj = (const float*)d_in[4];   // [256]
  const float* rpb0   = (const float*)d_in[5];   // [4,13,13]
  const float* rpb1   = (const float*)d_in[6];   // [4,13,13]
  float* out = (float*)d_out;                    // [2,56,56,256] fp32

  // ws layout (bf16 elems): wqkvT | wprojT | xb | qkv | attn  => ~15.8 MB
  uint16_t* wqkvT  = (uint16_t*)d_ws;                    // 768*256
  uint16_t* wprojT = wqkvT + 768 * 256;                  // 256*256
  uint16_t* xb     = wprojT + 256 * 256;                 // 6272*256
  uint16_t* qkv    = xb + (size_t)6272 * 256;            // 6272*768
  uint16_t* attn   = qkv + (size_t)6272 * 768;           // 6272*256

  convert_f32_bf16<<<dim3(784), 256, 0, stream>>>(x, xb);
  transpose_f32_bf16<<<dim3(4, 12), 256, 0, stream>>>(w_qkv, wqkvT, 256, 768);
  transpose_f32_bf16<<<dim3(4, 4),  256, 0, stream>>>(w_proj, wprojT, 256, 256);
  gemm_bt_bias<0><<<dim3(98, 12), 256, 0, stream>>>(xb, wqkvT, b_qkv, qkv, 768);
  natten_kernel<<<dim3(7, 7, 16), 256, 0, stream>>>(qkv, rpb0, rpb1, attn);
  gemm_bt_bias<1><<<dim3(98, 4), 256, 0, stream>>>(attn, wprojT, b_proj, out, 256);
}